// Round 1
// baseline (125.994 us; speedup 1.0000x reference)
//
#include <hip/hip_runtime.h>

// HungarianMatcher cost matrix for DETR-style matching.
// C[q, t] = 5*L1(pred_box_q, tgt_box_t) + 2*(pos-neg focal cost at tgt class) - 2*GIoU
// Layout: one 256-thread block per query q (bs*nq = 14400 blocks).
//   Phase 1: threads 0..nc-1 compute the focal class-cost row (91 entries) into LDS.
//   Phase 2: threads stride over the 1600 targets; coalesced stores of C row.

#define BLOCK 256

__global__ __launch_bounds__(BLOCK) void matcher_kernel(
    const float* __restrict__ logits,   // [NQall, nc]
    const float* __restrict__ pboxes,   // [NQall, 4] cxcywh
    const float* __restrict__ tboxes,   // [nt, 4]    cxcywh
    const int*   __restrict__ tids,     // [nt]
    float*       __restrict__ out,      // [NQall, nt]
    int nc, int nt)
{
    __shared__ float s_cc[128];         // focal class cost * COST_CLASS, per class
    const int q   = blockIdx.x;
    const int tid = threadIdx.x;

    if (tid < nc) {
        float x = logits[(size_t)q * nc + tid];
        float p = 1.0f / (1.0f + __expf(-x));          // sigmoid
        float omp = 1.0f - p;
        float pos = 0.25f * omp * omp * (-__logf(p + 1e-8f));     // ALPHA=0.25, GAMMA=2
        float neg = 0.75f * p * p     * (-__logf(omp + 1e-8f));   // (1-ALPHA)=0.75
        s_cc[tid] = 2.0f * (pos - neg);                // COST_CLASS = 2 pre-applied
    }

    // Query box (cxcywh) -> xyxy + area; same 16B for all threads (L1 broadcast).
    const float4 qb = ((const float4*)pboxes)[q];
    const float qx0 = qb.x - 0.5f * qb.z, qy0 = qb.y - 0.5f * qb.w;
    const float qx1 = qb.x + 0.5f * qb.z, qy1 = qb.y + 0.5f * qb.w;
    const float qarea = qb.z * qb.w;

    __syncthreads();

    float* outq = out + (size_t)q * nt;
    for (int t = tid; t < nt; t += BLOCK) {
        const float4 tb = ((const float4*)tboxes)[t];
        const int id = tids[t];

        // L1 cost on raw cxcywh
        float l1 = fabsf(qb.x - tb.x) + fabsf(qb.y - tb.y)
                 + fabsf(qb.z - tb.z) + fabsf(qb.w - tb.w);

        // Target xyxy + area
        float tx0 = tb.x - 0.5f * tb.z, ty0 = tb.y - 0.5f * tb.w;
        float tx1 = tb.x + 0.5f * tb.z, ty1 = tb.y + 0.5f * tb.w;
        float tarea = tb.z * tb.w;

        // Intersection
        float ltx = fmaxf(qx0, tx0), lty = fmaxf(qy0, ty0);
        float rbx = fminf(qx1, tx1), rby = fminf(qy1, ty1);
        float iw = fmaxf(rbx - ltx, 0.0f), ih = fmaxf(rby - lty, 0.0f);
        float inter = iw * ih;
        float uni = qarea + tarea - inter;
        float iou = inter * __builtin_amdgcn_rcpf(uni);

        // Enclosing box
        float ex0 = fminf(qx0, tx0), ey0 = fminf(qy0, ty0);
        float ex1 = fmaxf(qx1, tx1), ey1 = fmaxf(qy1, ty1);
        float ew = fmaxf(ex1 - ex0, 0.0f), eh = fmaxf(ey1 - ey0, 0.0f);
        float earea = ew * eh;
        float giou = iou - (earea - uni) * __builtin_amdgcn_rcpf(earea);

        // C = 5*l1 + 2*cost_class + 2*(-giou); s_cc already has the 2x.
        outq[t] = 5.0f * l1 + s_cc[id] - 2.0f * giou;
    }
}

extern "C" void kernel_launch(void* const* d_in, const int* in_sizes, int n_in,
                              void* d_out, int out_size, void* d_ws, size_t ws_size,
                              hipStream_t stream) {
    const float* logits = (const float*)d_in[0];   // (16,900,91) fp32
    const float* pboxes = (const float*)d_in[1];   // (16,900,4)  fp32
    const float* tboxes = (const float*)d_in[2];   // (1600,4)    fp32
    const int*   tids   = (const int*)d_in[3];     // (1600,)     int

    const int nqall = in_sizes[1] / 4;             // 14400
    const int nt    = in_sizes[2] / 4;             // 1600
    const int nc    = in_sizes[0] / nqall;         // 91

    float* out = (float*)d_out;

    matcher_kernel<<<nqall, BLOCK, 0, stream>>>(logits, pboxes, tboxes, tids,
                                                out, nc, nt);
}

// Round 2
// 121.404 us; speedup vs baseline: 1.0378x; 1.0378x over previous
//
#include <hip/hip_runtime.h>

// HungarianMatcher cost matrix, register-blocked over targets.
// C[q,t] = 5*L1 + 2*focal_class_cost(tgt_id) - 2*GIoU, fp32 out [14400,1600].
//
// Structure: 1800 blocks x 256 threads; each block owns QPB=8 queries.
// Phase A: block computes 8x91 focal class costs into LDS (contiguous logits
//          sweep) and each thread stages its 7 targets (cxcywh + xyxy + id)
//          into REGISTERS once.
// Phase B: loop over the 8 queries; per (q, target-slot) the feed is only a
//          4B LDS gather (class cost) -- all box data already in regs.
// Stores: out[q][tid + k*256] -> 4B coalesced, perfectly balanced tail
// (k=6 active only for wave 0).

#define BLOCK 256
#define QPB 8
#define NC 91
#define NT 1600
#define TSLOTS ((NT + BLOCK - 1) / BLOCK)   // 7

__global__ __launch_bounds__(BLOCK, 4) void matcher_kernel(
    const float* __restrict__ logits,   // [14400, 91]
    const float* __restrict__ pboxes,   // [14400, 4] cxcywh
    const float* __restrict__ tboxes,   // [1600, 4]  cxcywh
    const int*   __restrict__ tids,     // [1600]
    float*       __restrict__ out)      // [14400, 1600]
{
    __shared__ float s_cc[QPB * NC];
    const int tid = threadIdx.x;
    const int q0  = blockIdx.x * QPB;

    // --- Phase A1: focal class costs for this block's 8 queries.
    // s_cc[q*91+c] maps to logits[q0*91 + i] -- one contiguous coalesced sweep.
    for (int i = tid; i < QPB * NC; i += BLOCK) {
        float x   = logits[(size_t)q0 * NC + i];
        float p   = 1.0f / (1.0f + __expf(-x));            // sigmoid
        float omp = 1.0f - p;
        float pos = 0.25f * omp * omp * (-__logf(p   + 1e-8f));
        float neg = 0.75f * p   * p   * (-__logf(omp + 1e-8f));
        s_cc[i] = 2.0f * (pos - neg);                      // COST_CLASS folded in
    }

    // --- Phase A2: stage this thread's 7 targets into registers.
    float4 tb[TSLOTS], xy[TSLOTS];
    int    ida[TSLOTS];
    #pragma unroll
    for (int k = 0; k < TSLOTS; ++k) {
        int t = tid + k * BLOCK;
        if (t < NT) {
            float4 b = ((const float4*)tboxes)[t];
            tb[k] = b;
            xy[k] = make_float4(fmaf(-0.5f, b.z, b.x), fmaf(-0.5f, b.w, b.y),
                                fmaf( 0.5f, b.z, b.x), fmaf( 0.5f, b.w, b.y));
            ida[k] = tids[t];
        }
    }
    __syncthreads();

    // --- Phase B: 8 queries x 7 register-resident targets.
    #pragma unroll 1
    for (int q = 0; q < QPB; ++q) {
        const int    qg = q0 + q;
        const float4 qb = ((const float4*)pboxes)[qg];     // same addr all lanes: L1 broadcast
        const float qx0 = fmaf(-0.5f, qb.z, qb.x), qy0 = fmaf(-0.5f, qb.w, qb.y);
        const float qx1 = fmaf( 0.5f, qb.z, qb.x), qy1 = fmaf( 0.5f, qb.w, qb.y);
        const float qarea = qb.z * qb.w;
        const float* cc   = s_cc + q * NC;
        float* outq = out + (size_t)qg * NT;

        #pragma unroll
        for (int k = 0; k < TSLOTS; ++k) {
            int t = tid + k * BLOCK;
            if (t < NT) {                                  // wave-uniform (k=6: wave 0 only)
                float4 b = tb[k], p = xy[k];

                // L1 on raw cxcywh (abs folds into add input modifiers)
                float l1 = fabsf(qb.x - b.x) + fabsf(qb.y - b.y)
                         + fabsf(qb.z - b.z) + fabsf(qb.w - b.w);

                float tarea = b.z * b.w;
                // intersection
                float iw = fminf(qx1, p.z) - fmaxf(qx0, p.x);
                float ih = fminf(qy1, p.w) - fmaxf(qy0, p.y);
                float inter = fmaxf(iw, 0.0f) * fmaxf(ih, 0.0f);
                float uni   = qarea + tarea - inter;
                float iou   = inter * __builtin_amdgcn_rcpf(uni);
                // enclosing box (always non-degenerate: no clamp needed)
                float ew = fmaxf(qx1, p.z) - fminf(qx0, p.x);
                float eh = fmaxf(qy1, p.w) - fminf(qy0, p.y);
                float earea = ew * eh;
                float giou  = iou - (earea - uni) * __builtin_amdgcn_rcpf(earea);

                outq[t] = fmaf(5.0f, l1, cc[ida[k]]) - 2.0f * giou;
            }
        }
    }
}

extern "C" void kernel_launch(void* const* d_in, const int* in_sizes, int n_in,
                              void* d_out, int out_size, void* d_ws, size_t ws_size,
                              hipStream_t stream) {
    const float* logits = (const float*)d_in[0];   // (16,900,91) fp32
    const float* pboxes = (const float*)d_in[1];   // (16,900,4)  fp32
    const float* tboxes = (const float*)d_in[2];   // (1600,4)    fp32
    const int*   tids   = (const int*)d_in[3];     // (1600,)     int32

    const int nqall = in_sizes[1] / 4;             // 14400
    float* out = (float*)d_out;

    matcher_kernel<<<nqall / QPB, BLOCK, 0, stream>>>(logits, pboxes, tboxes,
                                                      tids, out);
}